// Round 12
// baseline (936.706 us; speedup 1.0000x reference)
//
#include <hip/hip_runtime.h>
#include <stdint.h>

using bf16x8 = __attribute__((ext_vector_type(8))) short;
using f32x4  = __attribute__((ext_vector_type(4))) float;

#define DEVFN static __device__ __forceinline__
#define L2E 1.4426950408889634f

DEVFN unsigned short f2bf(float f){
  union { float f; unsigned u; } v; v.f = f;
  return (unsigned short)((v.u + 0x7FFFu + ((v.u >> 16) & 1u)) >> 16);
}
DEVFN float bf2f(unsigned short h){
  union { unsigned u; float f; } v; v.u = ((unsigned)h) << 16;
  return v.f;
}
DEVFN unsigned short cvt1(float a){
  unsigned r;
  asm("v_cvt_pk_bf16_f32 %0, %1, %2" : "=v"(r) : "v"(a), "v"(a));
  return (unsigned short)r;
}
DEVFN f32x4 mfma16(bf16x8 a, bf16x8 b, f32x4 c){
  return __builtin_amdgcn_mfma_f32_16x16x32_bf16(a, b, c, 0, 0, 0);
}
DEVFN float exp2_(float x){
#if __has_builtin(__builtin_amdgcn_exp2f)
  return __builtin_amdgcn_exp2f(x);
#else
  return __expf(x*0.6931471805599453f);
#endif
}
DEVFN float sig2_(float x){ return 1.f/(1.f + exp2_(-x)); }
DEVFN float tanh2_(float x){ return 1.f - 2.f/(1.f + exp2_(x)); }

DEVFN int swz(int ar, int bc){ return ar*128 + (((bc>>3) ^ (ar&7))*8) + (bc&7); }

// 16-lane butterfly sum via DPP (pure VALU, no DS ops).
// Steps: xor1 = quad_perm(1,0,3,2); xor2 = quad_perm(2,3,0,1);
// xor4 -> row_half_mirror (other quad is value-uniform after steps 1-2);
// xor8 -> row_mirror (other 8-group uniform after step 3).
DEVFN float dpp_red16(float x){
  int y;
  y = __builtin_amdgcn_mov_dpp(__float_as_int(x), 0xB1,  0xF, 0xF, true); x += __int_as_float(y);
  y = __builtin_amdgcn_mov_dpp(__float_as_int(x), 0x4E,  0xF, 0xF, true); x += __int_as_float(y);
  y = __builtin_amdgcn_mov_dpp(__float_as_int(x), 0x141, 0xF, 0xF, true); x += __int_as_float(y);
  y = __builtin_amdgcn_mov_dpp(__float_as_int(x), 0x140, 0xF, 0xF, true); x += __int_as_float(y);
  return x;
}

// ---------------- prep kernels ----------------

__global__ __launch_bounds__(256) void k_sentinel(float* out, int n){
  int i = blockIdx.x*256 + threadIdx.x;
  if(i < n) out[i] = (i==0) ? -12345.f : 0.f;
}

__global__ __launch_bounds__(256) void k_conv_bf16(const float* __restrict__ s,
                                                   unsigned short* __restrict__ d, int n8){
  const int i = blockIdx.x*256 + threadIdx.x;
  if(i >= n8) return;
  union { bf16x8 v; unsigned short q[8]; } u;
  #pragma unroll
  for(int e=0;e<8;e++) u.q[e] = f2bf(s[(size_t)i*8 + e]);
  *(bf16x8*)(d + (size_t)i*8) = u.v;
}

// X [32][12][4096][2] f32 -> XrE[t][col=b*2+f][m] bf16
__global__ __launch_bounds__(256) void k_build_xre(const float* __restrict__ X,
                                                   unsigned short* __restrict__ XrE){
  const int idx = blockIdx.x*256 + threadIdx.x;
  if(idx >= 12*64*512) return;
  const int mc = idx & 511, col = (idx>>9)&63, t = idx>>15;
  const int b = col>>1, f = col&1;
  union { bf16x8 v; unsigned short q[8]; } u;
  #pragma unroll
  for(int e=0;e<8;e++){
    const int m = mc*8 + e;
    u.q[e] = f2bf(X[(((size_t)b*12 + t)*4096 + m)*2 + f]);
  }
  *(bf16x8*)(XrE + ((size_t)t*64 + col)*4096 + mc*8) = u.v;
}

// R4-exact pack: B-fragment order, col = c*16 + (lane&15), hi/lo split,
// scaled L2E (z|r) / 2*L2E (h). Bias floats at P+73728 shorts.
__global__ __launch_bounds__(256) void k_pack_w(const float* __restrict__ eWz, const float* __restrict__ eWr,
                                                const float* __restrict__ eWh, const float* __restrict__ dWz,
                                                const float* __restrict__ dWr, const float* __restrict__ dWh,
                                                const float* __restrict__ ebz, const float* __restrict__ ebr,
                                                const float* __restrict__ ebh, const float* __restrict__ dbz,
                                                const float* __restrict__ dbr, const float* __restrict__ dbh,
                                                unsigned short* __restrict__ P){
  const int idx = blockIdx.x*256 + threadIdx.x;
  if(idx >= 36864){
    if(idx >= 36864 + 384) return;
    const int q = idx - 36864, which = q>>6, e = q&63;
    const float* src = (which==0)?ebz:(which==1)?ebr:(which==2)?ebh:
                       (which==3)?dbz:(which==4)?dbr:dbh;
    const float scale = (which==2 || which==5) ? 2.f*L2E : L2E;
    float* Pf = (float*)(P + 73728);
    Pf[q] = src[e]*scale;
    return;
  }
  int q, hi_off, in_dim, ncf; float scale; const float *Wa, *Wb;
  if(idx < 12288)      { q = idx;        hi_off = 0;     in_dim=68; ncf=8; Wa=eWz; Wb=eWr; scale=L2E; }
  else if(idx < 18432) { q = idx-12288;  hi_off = 24576; in_dim=68; ncf=4; Wa=eWh; Wb=nullptr; scale=2.f*L2E; }
  else if(idx < 30720) { q = idx-18432;  hi_off = 36864; in_dim=66; ncf=8; Wa=dWz; Wb=dWr; scale=L2E; }
  else                 { q = idx-30720;  hi_off = 61440; in_dim=66; ncf=4; Wa=dWh; Wb=nullptr; scale=2.f*L2E; }
  const int lane = (q>>3)&63, j = q&7, ksc = q>>9;
  const int ks = (ncf==8)? (ksc>>3) : (ksc>>2);
  const int c  = (ncf==8)? (ksc&7)  : (ksc&3);
  const int k = ks*32 + (lane>>4)*8 + j;
  const int col = c*16 + (lane&15);
  float w = 0.f;
  if(k < in_dim){
    if(ncf==8) w = (col<64)? Wa[k*64+col] : Wb[k*64+(col-64)];
    else       w = Wa[k*64+col];
  }
  w *= scale;
  const unsigned short hb = f2bf(w);
  const int lo_off = hi_off + ((ncf==8)? 12288 : 6144);
  P[hi_off + q] = hb;
  P[lo_off + q] = f2bf(w - bf2f(hb));
}

// ---------------- batched encoder diffusion GEMM (XCD-aware block swizzle) ----------------
__global__ __launch_bounds__(256)
void k_enc_gemm(const unsigned short* __restrict__ As,
                const unsigned short* __restrict__ Xr,
                float* __restrict__ Cp)
{
  constexpr int BM=64, BN=192, BK=64, KTOT=4096, ITERS=KTOT/BK;
  __shared__ __align__(16) unsigned short Abuf[2][BM*BK];
  __shared__ __align__(16) unsigned short Bbuf[2][BN*BK];
  const int tid=threadIdx.x, wv=tid>>6, l=tid&63;
  const int bid = blockIdx.x;
  const int vid = (bid&7)*64 + (bid>>3);
  const int mblk = vid>>2, nblk = vid&3;
  const int wr2 = (wv>>1)*32, wc2 = (wv&1)*96;

  bf16x8 ra[2], rb[6];
  auto load_regs = [&](int it){
    const int kb = it*BK;
    #pragma unroll
    for(int c=0;c<2;c++){
      const int d=c*256+tid, r=d>>3, j=d&7;
      ra[c] = *(const bf16x8*)(As + (size_t)(mblk*BM+r)*KTOT + kb + j*8);
    }
    #pragma unroll
    for(int c=0;c<6;c++){
      const int d=c*256+tid, col=d>>3, j=d&7;
      rb[c] = *(const bf16x8*)(Xr + (size_t)(nblk*BN+col)*KTOT + kb + j*8);
    }
  };

  const f32x4 zero4 = {0.f,0.f,0.f,0.f};
  f32x4 acc[2][6];
  #pragma unroll
  for(int a=0;a<2;a++)
    #pragma unroll
    for(int b=0;b<6;b++) acc[a][b]=zero4;

  load_regs(0);
  for(int it=0; it<ITERS; ++it){
    const int buf = it & 1;
    #pragma unroll
    for(int c=0;c<2;c++){
      const int d=c*256+tid, r=d>>3, j=d&7;
      *(bf16x8*)(&Abuf[buf][r*BK + ((j ^ (r&7))*8)]) = ra[c];
    }
    #pragma unroll
    for(int c=0;c<6;c++){
      const int d=c*256+tid, col=d>>3, j=d&7;
      *(bf16x8*)(&Bbuf[buf][col*BK + ((j ^ (col&7))*8)]) = rb[c];
    }
    __syncthreads();
    if(it+1 < ITERS) load_regs(it+1);
    #pragma unroll
    for(int ks=0; ks<2; ++ks){
      const int chq = ks*4 + (l>>4);
      bf16x8 af[2];
      #pragma unroll
      for(int rf=0;rf<2;rf++){
        const int arow = wr2 + rf*16 + (l&15);
        af[rf] = *(const bf16x8*)(&Abuf[buf][arow*BK + ((chq ^ (arow&7))*8)]);
      }
      #pragma unroll
      for(int cf=0;cf<6;cf++){
        const int bcol = wc2 + cf*16 + (l&15);
        bf16x8 bfr = *(const bf16x8*)(&Bbuf[buf][bcol*BK + ((chq ^ (bcol&7))*8)]);
        #pragma unroll
        for(int rf=0;rf<2;rf++) acc[rf][cf] = mfma16(af[rf], bfr, acc[rf][cf]);
      }
    }
    __syncthreads();
  }
  #pragma unroll
  for(int cf=0;cf<6;cf++){
    const int colg = nblk*BN + wc2 + cf*16 + (l&15);
    const int t = colg>>6, c64 = colg&63;
    #pragma unroll
    for(int rf=0;rf<2;rf++){
      const int row = mblk*BM + wr2 + rf*16 + (l>>4)*4;
      #pragma unroll
      for(int j=0;j<4;j++)
        Cp[((size_t)t*8192 + row + j)*64 + c64] = acc[rf][cf][j];
    }
  }
}

// ---------------- fused 12-step encoder (Wzr LDS, Whh+Whl global, DPP LN) ----------------
__global__ __launch_bounds__(256,3)
void k_enc_fused(float* __restrict__ hout,
                 const float* __restrict__ Cp,   // [12][8192][64]
                 const unsigned short* __restrict__ P,
                 const float* __restrict__ bzr, const float* __restrict__ bhf,
                 const float* __restrict__ g, const float* __restrict__ beta)
{
  __shared__ __align__(16) unsigned short A_[64*128];   // 16 KB
  __shared__ __align__(16) unsigned short Wzr[12288];   // 24 KB (zr hi)
  const unsigned short* Whh = P + 24576;                // h hi (global, L1)
  const unsigned short* Whl = P + 30720;                // h lo (global, L1)
  const int tid=threadIdx.x, wv=tid>>6, l=tid&63;
  const int q15 = l&15;
  const int rb = blockIdx.x*64, wr = wv*16, lrow0=(l>>4)*4;
  const f32x4 zero4 = {0.f,0.f,0.f,0.f};

  for(int i=tid; i<1536; i+=256) ((bf16x8*)Wzr)[i] = ((const bf16x8*)(P))[i];
  for(int z=tid; z<64*28; z+=256){
    const int r=z/28, col=68+(z%28);
    A_[swz(r,col)] = 0;
  }

  // hoist t-invariant constants into registers
  float bzr_r[8], bh_r[4], g_r[4], be_r[4];
  #pragma unroll
  for(int c=0;c<8;c++) bzr_r[c] = bzr[c*16+q15];
  #pragma unroll
  for(int c=0;c<4;c++){ bh_r[c]=bhf[c*16+q15]; g_r[c]=g[c*16+q15]; be_r[c]=beta[c*16+q15]; }
  int sta[4][4];
  #pragma unroll
  for(int c=0;c<4;c++)
    #pragma unroll
    for(int j=0;j<4;j++) sta[c][j] = swz(wr+lrow0+j, 4 + c*16 + q15);
  int ard[3];
  {
    const int arow = wr + q15;
    #pragma unroll
    for(int ks=0;ks<3;ks++) ard[ks] = arow*128 + (((ks*4+(l>>4)) ^ (arow&7))*8);
  }

  float hv[4][4];
  #pragma unroll
  for(int c=0;c<4;c++)
    #pragma unroll
    for(int j=0;j<4;j++) hv[c][j]=0.f;

  const int xr = tid>>2, xcol = tid&3;
  const int xgrow = rb + xr;
  const int xb = xgrow>>12, xn = xgrow&4095;
  const size_t xoff = ((size_t)(xcol>>1)*4096 + xn)*64 + ((xb<<1)|(xcol&1));
  const int xsw = swz(xr, xcol);

  float xv = Cp[xoff];

  #pragma unroll 1
  for(int t=0;t<12;t++){
    __syncthreads();   // protects prev-step readers; t=0: orders W-stage + pad
    A_[xsw] = cvt1(xv);
    if(t < 11) xv = Cp[(size_t)(t+1)*524288 + xoff];
    #pragma unroll
    for(int c=0;c<4;c++){
      #pragma unroll
      for(int j=0;j<4;j++)
        A_[sta[c][j]] = cvt1(hv[c][j]);
    }
    __syncthreads();
    // phase 1: z|r (W hi only, from LDS)
    bf16x8 af[3];
    #pragma unroll
    for(int ks=0;ks<3;ks++)
      af[ks]=*(const bf16x8*)(&A_[ard[ks]]);
    float zv[4][4], rv[4][4];
    #pragma unroll
    for(int c=0;c<8;c++){
      f32x4 acc=zero4;
      #pragma unroll
      for(int ks=0;ks<3;ks++){
        const bf16x8 whi=*(const bf16x8*)(&Wzr[(((ks*8+c)*64+l)*8)]);
        acc=mfma16(af[ks],whi,acc);
      }
      #pragma unroll
      for(int j=0;j<4;j++){
        const float s=sig2_(acc[j]+bzr_r[c]);
        if(c<4) zv[c][j]=s; else rv[c-4][j]=s;
      }
    }
    __syncthreads();
    // restage r*h
    #pragma unroll
    for(int c=0;c<4;c++){
      #pragma unroll
      for(int j=0;j<4;j++)
        A_[sta[c][j]] = cvt1(rv[c][j]*hv[c][j]);
    }
    __syncthreads();
    // phase 2: h_tilde (W hi + lo from global/L1)
    float ht[4][4];
    {
      bf16x8 a2[3];
      #pragma unroll
      for(int ks=0;ks<3;ks++)
        a2[ks]=*(const bf16x8*)(&A_[ard[ks]]);
      #pragma unroll
      for(int c=0;c<4;c++){
        f32x4 acc=zero4;
        #pragma unroll
        for(int ks=0;ks<3;ks++){
          const bf16x8 whi=*(const bf16x8*)(Whh + (((ks*4+c)*64+l)*8));
          const bf16x8 wlo=*(const bf16x8*)(Whl + (((ks*4+c)*64+l)*8));
          acc=mfma16(a2[ks],whi,acc);
          acc=mfma16(a2[ks],wlo,acc);
        }
        #pragma unroll
        for(int j=0;j<4;j++) ht[c][j]=tanh2_(acc[j]+bh_r[c]);
      }
    }
    // blend + LayerNorm (DPP reduce)
    #pragma unroll
    for(int j=0;j<4;j++){
      float hn[4], s=0.f, q2=0.f;
      #pragma unroll
      for(int c=0;c<4;c++){
        const float v=(1.f-zv[c][j])*hv[c][j] + zv[c][j]*ht[c][j];
        hn[c]=v; s+=v; q2+=v*v;
      }
      s = dpp_red16(s); q2 = dpp_red16(q2);
      const float mu=s*(1.f/64.f);
      const float var=q2*(1.f/64.f)-mu*mu;
      const float rs=rsqrtf(var+1e-5f);
      #pragma unroll
      for(int c=0;c<4;c++)
        hv[c][j]=(hn[c]-mu)*rs*g_r[c] + be_r[c];
    }
  }
  #pragma unroll
  for(int c=0;c<4;c++){
    const int col=c*16+q15;
    #pragma unroll
    for(int j=0;j<4;j++)
      hout[(size_t)(rb+wr+lrow0+j)*64 + col] = hv[c][j];
  }
}

// ---------------- decoder diffusion GEMM (split-K=4, R9-exact) ----------------
template<int NC>
__global__ __launch_bounds__(256)
void k_diff_gemm(const unsigned short* __restrict__ As,
                 const unsigned short* __restrict__ Xr,
                 float* __restrict__ Cpart)
{
  constexpr int NCf = NC/16;
  constexpr int BCN = (NC==64)?2:1;
  constexpr int KTOT = 4096, BM=64, BK=64, KPB=1024, ITERS=KPB/BK;
  __shared__ __align__(16) unsigned short Abuf[2][BM*BK];
  __shared__ __align__(16) unsigned short Bbuf[2][NC*BK];
  const int tid = threadIdx.x, wv = tid>>6, l = tid&63;
  const int mblk = blockIdx.x, split = blockIdx.y;
  const int k0 = split*KPB;

  bf16x8 ra[2], rb[BCN];
  auto load_regs = [&](int it){
    const int kb = k0 + it*BK;
    #pragma unroll
    for(int c=0;c<2;c++){
      const int d = c*256 + tid, r = d>>3, j = d&7;
      ra[c] = *(const bf16x8*)(As + (size_t)(mblk*BM + r)*KTOT + (kb + j*8));
    }
    #pragma unroll
    for(int c=0;c<BCN;c++){
      const int d = c*256 + tid, col = d>>3, j = d&7;
      rb[c] = *(const bf16x8*)(Xr + (size_t)col*KTOT + (kb + j*8));
    }
  };

  const f32x4 zero4 = {0.f,0.f,0.f,0.f};
  f32x4 acc[NCf];
  #pragma unroll
  for(int c=0;c<NCf;c++) acc[c] = zero4;

  load_regs(0);
  for(int it=0; it<ITERS; ++it){
    const int buf = it & 1;
    #pragma unroll
    for(int c=0;c<2;c++){
      const int d = c*256 + tid, r = d>>3, j = d&7;
      *(bf16x8*)(&Abuf[buf][r*BK + ((j ^ (r&7))*8)]) = ra[c];
    }
    #pragma unroll
    for(int c=0;c<BCN;c++){
      const int d = c*256 + tid, col = d>>3, j = d&7;
      *(bf16x8*)(&Bbuf[buf][col*BK + ((j ^ (col&7))*8)]) = rb[c];
    }
    __syncthreads();
    if(it+1 < ITERS) load_regs(it+1);
    const int arow = wv*16 + (l&15);
    #pragma unroll
    for(int ks=0; ks<2; ++ks){
      const int chq = ks*4 + (l>>4);
      bf16x8 a = *(const bf16x8*)(&Abuf[buf][arow*BK + ((chq ^ (arow&7))*8)]);
      #pragma unroll
      for(int c=0;c<NCf;c++){
        const int cc = c*16 + (l&15);
        bf16x8 b = *(const bf16x8*)(&Bbuf[buf][cc*BK + ((chq ^ (cc&7))*8)]);
        acc[c] = mfma16(a, b, acc[c]);
      }
    }
    __syncthreads();
  }
  const int rbase = mblk*BM + wv*16 + (l>>4)*4;
  #pragma unroll
  for(int c=0;c<NCf;c++){
    const int col = c*16 + (l&15);
    #pragma unroll
    for(int j=0;j<4;j++)
      Cpart[((size_t)split*8192 + rbase + j)*NC + col] = acc[c][j];
  }
}

// ---------------- decoder fused GRU cell (Wzr LDS, Whh+Whl global, DPP) ----------------
template<int XC, bool DEC>
__global__ __launch_bounds__(256)
void k_gru(float* __restrict__ h,
           const float* __restrict__ Cpart,
           const unsigned short* __restrict__ Wzr_hi, const unsigned short* __restrict__ Wzr_lo,
           const unsigned short* __restrict__ Wh_hi,  const unsigned short* __restrict__ Wh_lo,
           const float* __restrict__ bzr, const float* __restrict__ bhf,
           const float* __restrict__ g, const float* __restrict__ beta,
           const float* __restrict__ fcW, const float* __restrict__ fcb,
           float* __restrict__ out, unsigned short* __restrict__ XrD, int t)
{
  constexpr int NCIN = (XC==4)?64:32;
  constexpr int PAD0 = XC + 64;
  __shared__ __align__(16) unsigned short A_[64*128];   // 16 KB
  __shared__ __align__(16) unsigned short Wzr[12288];   // 24 KB (zr hi)
  (void)Wzr_lo;
  const unsigned short* Whh = Wh_hi;                    // global/L1
  const int tid = threadIdx.x, wv = tid>>6, l = tid&63;
  const int rb = blockIdx.x * 64;
  const int wr = wv*16, lrow0 = (l>>4)*4;
  const f32x4 zero4 = {0.f,0.f,0.f,0.f};

  for(int i=tid; i<1536; i+=256) ((bf16x8*)Wzr)[i] = ((const bf16x8*)Wzr_hi)[i];
  for(int z=tid; z<64*(96-PAD0); z+=256){
    const int r = z/(96-PAD0), col = PAD0 + z%(96-PAD0);
    A_[swz(r,col)] = 0;
  }
  if(tid < 64*XC){
    const int r = tid/XC, col = tid%XC;
    const int grow = rb + r;
    const int b = grow >> 12, n = grow & 4095;
    const int sup = (XC==4)? (col>>1) : col;
    const int ccol = (XC==4)? ((b<<1) | (col&1)) : b;
    const size_t cr = (size_t)sup*4096 + n;
    const float v = Cpart[(0*(size_t)8192 + cr)*NCIN + ccol]
                  + Cpart[(1*(size_t)8192 + cr)*NCIN + ccol]
                  + Cpart[(2*(size_t)8192 + cr)*NCIN + ccol]
                  + Cpart[(3*(size_t)8192 + cr)*NCIN + ccol];
    A_[swz(r,col)] = cvt1(v);
  }
  float hv[4][4];
  #pragma unroll
  for(int c=0;c<4;c++){
    #pragma unroll
    for(int j=0;j<4;j++){
      const float hval = h[(size_t)(rb + wr + lrow0 + j)*64 + c*16 + (l&15)];
      hv[c][j] = hval;
      A_[swz(wr+lrow0+j, XC + c*16 + (l&15))] = cvt1(hval);
    }
  }
  __syncthreads();

  bf16x8 af[3];
  {
    const int arow = wr + (l&15);
    #pragma unroll
    for(int ks=0;ks<3;ks++)
      af[ks] = *(const bf16x8*)(&A_[arow*128 + (((ks*4 + (l>>4)) ^ (arow&7))*8)]);
  }
  float zv[4][4], rv[4][4];
  #pragma unroll
  for(int c=0;c<8;c++){
    f32x4 acc = zero4;
    #pragma unroll
    for(int ks=0;ks<3;ks++){
      const bf16x8 whi = *(const bf16x8*)(&Wzr[(((ks*8 + c)*64 + l)*8)]);
      acc = mfma16(af[ks], whi, acc);
    }
    const float bias = bzr[c*16 + (l&15)];
    #pragma unroll
    for(int j=0;j<4;j++){
      const float s = sig2_(acc[j] + bias);
      if(c<4) zv[c][j] = s; else rv[c-4][j] = s;
    }
  }
  __syncthreads();

  #pragma unroll
  for(int c=0;c<4;c++){
    #pragma unroll
    for(int j=0;j<4;j++)
      A_[swz(wr+lrow0+j, XC + c*16 + (l&15))] = cvt1(rv[c][j]*hv[c][j]);
  }
  __syncthreads();

  float ht[4][4];
  {
    const int arow = wr + (l&15);
    bf16x8 a2[3];
    #pragma unroll
    for(int ks=0;ks<3;ks++)
      a2[ks] = *(const bf16x8*)(&A_[arow*128 + (((ks*4 + (l>>4)) ^ (arow&7))*8)]);
    #pragma unroll
    for(int c=0;c<4;c++){
      f32x4 acc = zero4;
      #pragma unroll
      for(int ks=0;ks<3;ks++){
        const bf16x8 whi = *(const bf16x8*)(Whh + (((ks*4 + c)*64 + l)*8));
        const bf16x8 wlo = *(const bf16x8*)(Wh_lo + (((ks*4 + c)*64 + l)*8));
        acc = mfma16(a2[ks], whi, acc);
        acc = mfma16(a2[ks], wlo, acc);
      }
      const float bias = bhf[c*16 + (l&15)];
      #pragma unroll
      for(int j=0;j<4;j++) ht[c][j] = tanh2_(acc[j] + bias);
    }
  }

  float onew[4][4];
  #pragma unroll
  for(int j=0;j<4;j++){
    float hn[4];
    float s=0.f, q2=0.f;
    #pragma unroll
    for(int c=0;c<4;c++){
      const float v = (1.f - zv[c][j])*hv[c][j] + zv[c][j]*ht[c][j];
      hn[c]=v; s += v; q2 += v*v;
    }
    s = dpp_red16(s); q2 = dpp_red16(q2);
    const float mu = s*(1.f/64.f);
    const float var = q2*(1.f/64.f) - mu*mu;
    const float rs = rsqrtf(var + 1e-5f);
    #pragma unroll
    for(int c=0;c<4;c++){
      const int col = c*16 + (l&15);
      onew[c][j] = (hn[c]-mu)*rs*g[col] + beta[col];
    }
  }
  #pragma unroll
  for(int c=0;c<4;c++){
    const int col = c*16 + (l&15);
    #pragma unroll
    for(int j=0;j<4;j++)
      h[(size_t)(rb + wr + lrow0 + j)*64 + col] = onew[c][j];
  }
  if constexpr (DEC){
    #pragma unroll
    for(int j=0;j<4;j++){
      float fs = 0.f;
      #pragma unroll
      for(int c=0;c<4;c++) fs += onew[c][j]*fcW[c*16 + (l&15)];
      fs = dpp_red16(fs);
      if((l&15)==0){
        const int grow = rb + wr + lrow0 + j;
        const int b = grow>>12, n = grow & 4095;
        const float y = fs + fcb[0];
        out[((size_t)b*12 + t)*4096 + n] = y;
        XrD[(size_t)b*4096 + n] = f2bf(y);
      }
    }
  }
}

// ---------------- launch ----------------

extern "C" void kernel_launch(void* const* d_in, const int* in_sizes, int n_in,
                              void* d_out, int out_size, void* d_ws, size_t ws_size,
                              hipStream_t stream)
{
  (void)in_sizes; (void)n_in;
  const float* X   = (const float*)d_in[0];
  const float* sup = (const float*)d_in[1];
  const float* eWz = (const float*)d_in[2];
  const float* ebz = (const float*)d_in[3];
  const float* eWr = (const float*)d_in[4];
  const float* ebr = (const float*)d_in[5];
  const float* eWh = (const float*)d_in[6];
  const float* ebh = (const float*)d_in[7];
  const float* eg  = (const float*)d_in[8];
  const float* ebt = (const float*)d_in[9];
  const float* dWz = (const float*)d_in[10];
  const float* dbz = (const float*)d_in[11];
  const float* dWr = (const float*)d_in[12];
  const float* dbr = (const float*)d_in[13];
  const float* dWh = (const float*)d_in[14];
  const float* dbh = (const float*)d_in[15];
  const float* dg  = (const float*)d_in[16];
  const float* dbt = (const float*)d_in[17];
  const float* fcW = (const float*)d_in[18];
  const float* fcb = (const float*)d_in[19];
  float* out = (float*)d_out;

  char* ws = (char*)d_ws;
  const size_t OFF_AS  = 0;                    // 67,108,864  As bf16 [8192][4096]
  const size_t OFF_H   = 67108864;             // 33,554,432  h f32 (logical layout)
  const size_t OFF_CPE = 100663296;            // 25,165,824  Cp_enc f32 [12][8192][64]
  const size_t OFF_CPD = 125829120;            //  4,194,304  Cp_dec f32 [4][8192][32]
  const size_t OFF_XRE = 130023424;            //  6,291,456  XrE bf16
  const size_t OFF_XRD = 136314880;            //    262,144  XrD bf16
  const size_t OFF_P   = 136577024;            //    147,456 B shorts + 1,536 B bias floats
  const size_t NEED    = OFF_P + 147456 + 1536;
  if(ws_size < NEED){
    k_sentinel<<<(out_size+255)/256,256,0,stream>>>(out, out_size);
    return;
  }
  unsigned short* As  = (unsigned short*)(ws + OFF_AS);
  float* h            = (float*)(ws + OFF_H);
  float* CpE          = (float*)(ws + OFF_CPE);
  float* CpD          = (float*)(ws + OFF_CPD);
  unsigned short* XrE = (unsigned short*)(ws + OFF_XRE);
  unsigned short* XrD = (unsigned short*)(ws + OFF_XRD);
  unsigned short* P   = (unsigned short*)(ws + OFF_P);
  const float* Pf     = (const float*)(ws + OFF_P + 147456);

  k_conv_bf16<<<16384,256,0,stream>>>(sup, As, 4194304);
  k_pack_w<<<146,256,0,stream>>>(eWz,eWr,eWh,dWz,dWr,dWh,
                                 ebz,ebr,ebh,dbz,dbr,dbh,P);
  k_build_xre<<<1536,256,0,stream>>>(X, XrE);

  // encoder: one batched diffusion GEMM + one fused 12-step GRU kernel
  k_enc_gemm<<<512,256,0,stream>>>(As, XrE, CpE);
  k_enc_fused<<<2048,256,0,stream>>>(h, CpE, P, Pf+0, Pf+128, eg, ebt);

  // decoder: sequential (y feeds back through global diffusion)
  hipMemsetAsync(CpD, 0, 4194304, stream);   // t=0: y=0 -> x_cat=0
  for(int t=0;t<12;t++){
    if(t>0) k_diff_gemm<32><<<dim3(128,4),256,0,stream>>>(As, XrD, CpD);
    k_gru<2,true><<<2048,256,0,stream>>>(h, CpD, P+36864, P+49152, P+61440, P+67584,
        Pf+192, Pf+320, dg, dbt, fcW, fcb, out, XrD, t);
  }
}

// Round 13
// 861.810 us; speedup vs baseline: 1.0869x; 1.0869x over previous
//
#include <hip/hip_runtime.h>
#include <stdint.h>

using bf16x8 = __attribute__((ext_vector_type(8))) short;
using f32x4  = __attribute__((ext_vector_type(4))) float;

#define DEVFN static __device__ __forceinline__
#define L2E 1.4426950408889634f

DEVFN unsigned short f2bf(float f){
  union { float f; unsigned u; } v; v.f = f;
  return (unsigned short)((v.u + 0x7FFFu + ((v.u >> 16) & 1u)) >> 16);
}
DEVFN float bf2f(unsigned short h){
  union { unsigned u; float f; } v; v.u = ((unsigned)h) << 16;
  return v.f;
}
DEVFN unsigned short cvt1(float a){
  unsigned r;
  asm("v_cvt_pk_bf16_f32 %0, %1, %2" : "=v"(r) : "v"(a), "v"(a));
  return (unsigned short)r;
}
DEVFN f32x4 mfma16(bf16x8 a, bf16x8 b, f32x4 c){
  return __builtin_amdgcn_mfma_f32_16x16x32_bf16(a, b, c, 0, 0, 0);
}
DEVFN float exp2_(float x){
#if __has_builtin(__builtin_amdgcn_exp2f)
  return __builtin_amdgcn_exp2f(x);
#else
  return __expf(x*0.6931471805599453f);
#endif
}
DEVFN float sig2_(float x){ return 1.f/(1.f + exp2_(-x)); }
DEVFN float tanh2_(float x){ return 1.f - 2.f/(1.f + exp2_(x)); }

DEVFN int swz(int ar, int bc){ return ar*128 + (((bc>>3) ^ (ar&7))*8) + (bc&7); }

// 16-lane butterfly sum via DPP (pure VALU, no DS ops).
DEVFN float dpp_red16(float x){
  int y;
  y = __builtin_amdgcn_mov_dpp(__float_as_int(x), 0xB1,  0xF, 0xF, true); x += __int_as_float(y);
  y = __builtin_amdgcn_mov_dpp(__float_as_int(x), 0x4E,  0xF, 0xF, true); x += __int_as_float(y);
  y = __builtin_amdgcn_mov_dpp(__float_as_int(x), 0x141, 0xF, 0xF, true); x += __int_as_float(y);
  y = __builtin_amdgcn_mov_dpp(__float_as_int(x), 0x140, 0xF, 0xF, true); x += __int_as_float(y);
  return x;
}

// ---------------- prep kernels ----------------

__global__ __launch_bounds__(256) void k_sentinel(float* out, int n){
  int i = blockIdx.x*256 + threadIdx.x;
  if(i < n) out[i] = (i==0) ? -12345.f : 0.f;
}

__global__ __launch_bounds__(256) void k_conv_bf16(const float* __restrict__ s,
                                                   unsigned short* __restrict__ d, int n8){
  const int i = blockIdx.x*256 + threadIdx.x;
  if(i >= n8) return;
  union { bf16x8 v; unsigned short q[8]; } u;
  #pragma unroll
  for(int e=0;e<8;e++) u.q[e] = f2bf(s[(size_t)i*8 + e]);
  *(bf16x8*)(d + (size_t)i*8) = u.v;
}

// X [32][12][4096][2] f32 -> XrE[t][col=b*2+f][m] bf16
__global__ __launch_bounds__(256) void k_build_xre(const float* __restrict__ X,
                                                   unsigned short* __restrict__ XrE){
  const int idx = blockIdx.x*256 + threadIdx.x;
  if(idx >= 12*64*512) return;
  const int mc = idx & 511, col = (idx>>9)&63, t = idx>>15;
  const int b = col>>1, f = col&1;
  union { bf16x8 v; unsigned short q[8]; } u;
  #pragma unroll
  for(int e=0;e<8;e++){
    const int m = mc*8 + e;
    u.q[e] = f2bf(X[(((size_t)b*12 + t)*4096 + m)*2 + f]);
  }
  *(bf16x8*)(XrE + ((size_t)t*64 + col)*4096 + mc*8) = u.v;
}

// R4-exact pack: B-fragment order, col = c*16 + (lane&15), hi/lo split,
// scaled L2E (z|r) / 2*L2E (h). Bias floats at P+73728 shorts.
__global__ __launch_bounds__(256) void k_pack_w(const float* __restrict__ eWz, const float* __restrict__ eWr,
                                                const float* __restrict__ eWh, const float* __restrict__ dWz,
                                                const float* __restrict__ dWr, const float* __restrict__ dWh,
                                                const float* __restrict__ ebz, const float* __restrict__ ebr,
                                                const float* __restrict__ ebh, const float* __restrict__ dbz,
                                                const float* __restrict__ dbr, const float* __restrict__ dbh,
                                                unsigned short* __restrict__ P){
  const int idx = blockIdx.x*256 + threadIdx.x;
  if(idx >= 36864){
    if(idx >= 36864 + 384) return;
    const int q = idx - 36864, which = q>>6, e = q&63;
    const float* src = (which==0)?ebz:(which==1)?ebr:(which==2)?ebh:
                       (which==3)?dbz:(which==4)?dbr:dbh;
    const float scale = (which==2 || which==5) ? 2.f*L2E : L2E;
    float* Pf = (float*)(P + 73728);
    Pf[q] = src[e]*scale;
    return;
  }
  int q, hi_off, in_dim, ncf; float scale; const float *Wa, *Wb;
  if(idx < 12288)      { q = idx;        hi_off = 0;     in_dim=68; ncf=8; Wa=eWz; Wb=eWr; scale=L2E; }
  else if(idx < 18432) { q = idx-12288;  hi_off = 24576; in_dim=68; ncf=4; Wa=eWh; Wb=nullptr; scale=2.f*L2E; }
  else if(idx < 30720) { q = idx-18432;  hi_off = 36864; in_dim=66; ncf=8; Wa=dWz; Wb=dWr; scale=L2E; }
  else                 { q = idx-30720;  hi_off = 61440; in_dim=66; ncf=4; Wa=dWh; Wb=nullptr; scale=2.f*L2E; }
  const int lane = (q>>3)&63, j = q&7, ksc = q>>9;
  const int ks = (ncf==8)? (ksc>>3) : (ksc>>2);
  const int c  = (ncf==8)? (ksc&7)  : (ksc&3);
  const int k = ks*32 + (lane>>4)*8 + j;
  const int col = c*16 + (lane&15);
  float w = 0.f;
  if(k < in_dim){
    if(ncf==8) w = (col<64)? Wa[k*64+col] : Wb[k*64+(col-64)];
    else       w = Wa[k*64+col];
  }
  w *= scale;
  const unsigned short hb = f2bf(w);
  const int lo_off = hi_off + ((ncf==8)? 12288 : 6144);
  P[hi_off + q] = hb;
  P[lo_off + q] = f2bf(w - bf2f(hb));
}

// ---------------- batched encoder diffusion GEMM (XCD-aware block swizzle) ----------------
__global__ __launch_bounds__(256)
void k_enc_gemm(const unsigned short* __restrict__ As,
                const unsigned short* __restrict__ Xr,
                float* __restrict__ Cp)
{
  constexpr int BM=64, BN=192, BK=64, KTOT=4096, ITERS=KTOT/BK;
  __shared__ __align__(16) unsigned short Abuf[2][BM*BK];
  __shared__ __align__(16) unsigned short Bbuf[2][BN*BK];
  const int tid=threadIdx.x, wv=tid>>6, l=tid&63;
  const int bid = blockIdx.x;
  const int vid = (bid&7)*64 + (bid>>3);
  const int mblk = vid>>2, nblk = vid&3;
  const int wr2 = (wv>>1)*32, wc2 = (wv&1)*96;

  bf16x8 ra[2], rb[6];
  auto load_regs = [&](int it){
    const int kb = it*BK;
    #pragma unroll
    for(int c=0;c<2;c++){
      const int d=c*256+tid, r=d>>3, j=d&7;
      ra[c] = *(const bf16x8*)(As + (size_t)(mblk*BM+r)*KTOT + kb + j*8);
    }
    #pragma unroll
    for(int c=0;c<6;c++){
      const int d=c*256+tid, col=d>>3, j=d&7;
      rb[c] = *(const bf16x8*)(Xr + (size_t)(nblk*BN+col)*KTOT + kb + j*8);
    }
  };

  const f32x4 zero4 = {0.f,0.f,0.f,0.f};
  f32x4 acc[2][6];
  #pragma unroll
  for(int a=0;a<2;a++)
    #pragma unroll
    for(int b=0;b<6;b++) acc[a][b]=zero4;

  load_regs(0);
  for(int it=0; it<ITERS; ++it){
    const int buf = it & 1;
    #pragma unroll
    for(int c=0;c<2;c++){
      const int d=c*256+tid, r=d>>3, j=d&7;
      *(bf16x8*)(&Abuf[buf][r*BK + ((j ^ (r&7))*8)]) = ra[c];
    }
    #pragma unroll
    for(int c=0;c<6;c++){
      const int d=c*256+tid, col=d>>3, j=d&7;
      *(bf16x8*)(&Bbuf[buf][col*BK + ((j ^ (col&7))*8)]) = rb[c];
    }
    __syncthreads();
    if(it+1 < ITERS) load_regs(it+1);
    #pragma unroll
    for(int ks=0; ks<2; ++ks){
      const int chq = ks*4 + (l>>4);
      bf16x8 af[2];
      #pragma unroll
      for(int rf=0;rf<2;rf++){
        const int arow = wr2 + rf*16 + (l&15);
        af[rf] = *(const bf16x8*)(&Abuf[buf][arow*BK + ((chq ^ (arow&7))*8)]);
      }
      #pragma unroll
      for(int cf=0;cf<6;cf++){
        const int bcol = wc2 + cf*16 + (l&15);
        bf16x8 bfr = *(const bf16x8*)(&Bbuf[buf][bcol*BK + ((chq ^ (bcol&7))*8)]);
        #pragma unroll
        for(int rf=0;rf<2;rf++) acc[rf][cf] = mfma16(af[rf], bfr, acc[rf][cf]);
      }
    }
    __syncthreads();
  }
  #pragma unroll
  for(int cf=0;cf<6;cf++){
    const int colg = nblk*BN + wc2 + cf*16 + (l&15);
    const int t = colg>>6, c64 = colg&63;
    #pragma unroll
    for(int rf=0;rf<2;rf++){
      const int row = mblk*BM + wr2 + rf*16 + (l>>4)*4;
      #pragma unroll
      for(int j=0;j<4;j++)
        Cp[((size_t)t*8192 + row + j)*64 + c64] = acc[rf][cf][j];
    }
  }
}

// ---------------- fused 12-step encoder (wave-local A-tile, barrier-free loop) ----------------
// All in-loop LDS accesses touch only the calling wave's 16 rows of A_;
// within-wave ordering is guaranteed by the in-order LDS pipe + compiler lgkmcnt.
__global__ __launch_bounds__(256,3)
void k_enc_fused(float* __restrict__ hout,
                 const float* __restrict__ Cp,   // [12][8192][64]
                 const unsigned short* __restrict__ P,
                 const float* __restrict__ bzr, const float* __restrict__ bhf,
                 const float* __restrict__ g, const float* __restrict__ beta)
{
  __shared__ __align__(16) unsigned short A_[64*128];   // 16 KB (wave-partitioned)
  __shared__ __align__(16) unsigned short Wzr[12288];   // 24 KB (zr hi)
  __shared__ __align__(16) unsigned short Whh[6144];    // 12 KB (h hi)
  const unsigned short* Whl = P + 30720;                // h lo (global, L1)
  const int tid=threadIdx.x, wv=tid>>6, l=tid&63;
  const int q15 = l&15;
  const int rb = blockIdx.x*64, wr = wv*16, lrow0=(l>>4)*4;
  const f32x4 zero4 = {0.f,0.f,0.f,0.f};

  for(int i=tid; i<1536; i+=256) ((bf16x8*)Wzr)[i] = ((const bf16x8*)(P))[i];
  for(int i=tid; i<768;  i+=256) ((bf16x8*)Whh)[i] = ((const bf16x8*)(P+24576))[i];
  for(int z=tid; z<64*28; z+=256){
    const int r=z/28, col=68+(z%28);
    A_[swz(r,col)] = 0;
  }

  float bzr_r[8], bh_r[4], g_r[4], be_r[4];
  #pragma unroll
  for(int c=0;c<8;c++) bzr_r[c] = bzr[c*16+q15];
  #pragma unroll
  for(int c=0;c<4;c++){ bh_r[c]=bhf[c*16+q15]; g_r[c]=g[c*16+q15]; be_r[c]=beta[c*16+q15]; }
  int sta[4][4];
  #pragma unroll
  for(int c=0;c<4;c++)
    #pragma unroll
    for(int j=0;j<4;j++) sta[c][j] = swz(wr+lrow0+j, 4 + c*16 + q15);
  int ard[3];
  {
    const int arow = wr + q15;
    #pragma unroll
    for(int ks=0;ks<3;ks++) ard[ks] = arow*128 + (((ks*4+(l>>4)) ^ (arow&7))*8);
  }

  float hv[4][4];
  #pragma unroll
  for(int c=0;c<4;c++)
    #pragma unroll
    for(int j=0;j<4;j++) hv[c][j]=0.f;

  const int xr = tid>>2, xcol = tid&3;   // xr in wave's own 16-row band
  const int xgrow = rb + xr;
  const int xb = xgrow>>12, xn = xgrow&4095;
  const size_t xoff = ((size_t)(xcol>>1)*4096 + xn)*64 + ((xb<<1)|(xcol&1));
  const int xsw = swz(xr, xcol);

  float xv = Cp[xoff];

  __syncthreads();   // single barrier: cross-wave W-stage + pad init

  #pragma unroll 1
  for(int t=0;t<12;t++){
    // stage [x|h] into this wave's A_ rows (wave-local; no barrier)
    A_[xsw] = cvt1(xv);
    if(t < 11) xv = Cp[(size_t)(t+1)*524288 + xoff];
    #pragma unroll
    for(int c=0;c<4;c++){
      #pragma unroll
      for(int j=0;j<4;j++)
        A_[sta[c][j]] = cvt1(hv[c][j]);
    }
    // phase 1: z|r (W hi only, from LDS)
    bf16x8 af[3];
    #pragma unroll
    for(int ks=0;ks<3;ks++)
      af[ks]=*(const bf16x8*)(&A_[ard[ks]]);
    float zv[4][4], rv[4][4];
    #pragma unroll
    for(int c=0;c<8;c++){
      f32x4 acc=zero4;
      #pragma unroll
      for(int ks=0;ks<3;ks++){
        const bf16x8 whi=*(const bf16x8*)(&Wzr[(((ks*8+c)*64+l)*8)]);
        acc=mfma16(af[ks],whi,acc);
      }
      #pragma unroll
      for(int j=0;j<4;j++){
        const float s=sig2_(acc[j]+bzr_r[c]);
        if(c<4) zv[c][j]=s; else rv[c-4][j]=s;
      }
    }
    // restage r*h (wave-local WAR: in-order LDS pipe)
    #pragma unroll
    for(int c=0;c<4;c++){
      #pragma unroll
      for(int j=0;j<4;j++)
        A_[sta[c][j]] = cvt1(rv[c][j]*hv[c][j]);
    }
    // phase 2: h_tilde (W hi LDS + lo global)
    float ht[4][4];
    {
      bf16x8 a2[3];
      #pragma unroll
      for(int ks=0;ks<3;ks++)
        a2[ks]=*(const bf16x8*)(&A_[ard[ks]]);
      #pragma unroll
      for(int c=0;c<4;c++){
        f32x4 acc=zero4;
        #pragma unroll
        for(int ks=0;ks<3;ks++){
          const bf16x8 whi=*(const bf16x8*)(&Whh[(((ks*4+c)*64+l)*8)]);
          const bf16x8 wlo=*(const bf16x8*)(Whl + (((ks*4+c)*64+l)*8));
          acc=mfma16(a2[ks],whi,acc);
          acc=mfma16(a2[ks],wlo,acc);
        }
        #pragma unroll
        for(int j=0;j<4;j++) ht[c][j]=tanh2_(acc[j]+bh_r[c]);
      }
    }
    // blend + LayerNorm (DPP reduce)
    #pragma unroll
    for(int j=0;j<4;j++){
      float hn[4], s=0.f, q2=0.f;
      #pragma unroll
      for(int c=0;c<4;c++){
        const float v=(1.f-zv[c][j])*hv[c][j] + zv[c][j]*ht[c][j];
        hn[c]=v; s+=v; q2+=v*v;
      }
      s = dpp_red16(s); q2 = dpp_red16(q2);
      const float mu=s*(1.f/64.f);
      const float var=q2*(1.f/64.f)-mu*mu;
      const float rs=rsqrtf(var+1e-5f);
      #pragma unroll
      for(int c=0;c<4;c++)
        hv[c][j]=(hn[c]-mu)*rs*g_r[c] + be_r[c];
    }
  }
  #pragma unroll
  for(int c=0;c<4;c++){
    const int col=c*16+q15;
    #pragma unroll
    for(int j=0;j<4;j++)
      hout[(size_t)(rb+wr+lrow0+j)*64 + col] = hv[c][j];
  }
}

// ---------------- decoder diffusion GEMM (split-K=4) ----------------
template<int NC>
__global__ __launch_bounds__(256)
void k_diff_gemm(const unsigned short* __restrict__ As,
                 const unsigned short* __restrict__ Xr,
                 float* __restrict__ Cpart)
{
  constexpr int NCf = NC/16;
  constexpr int BCN = (NC==64)?2:1;
  constexpr int KTOT = 4096, BM=64, BK=64, KPB=1024, ITERS=KPB/BK;
  __shared__ __align__(16) unsigned short Abuf[2][BM*BK];
  __shared__ __align__(16) unsigned short Bbuf[2][NC*BK];
  const int tid = threadIdx.x, wv = tid>>6, l = tid&63;
  const int mblk = blockIdx.x, split = blockIdx.y;
  const int k0 = split*KPB;

  bf16x8 ra[2], rb[BCN];
  auto load_regs = [&](int it){
    const int kb = k0 + it*BK;
    #pragma unroll
    for(int c=0;c<2;c++){
      const int d = c*256 + tid, r = d>>3, j = d&7;
      ra[c] = *(const bf16x8*)(As + (size_t)(mblk*BM + r)*KTOT + (kb + j*8));
    }
    #pragma unroll
    for(int c=0;c<BCN;c++){
      const int d = c*256 + tid, col = d>>3, j = d&7;
      rb[c] = *(const bf16x8*)(Xr + (size_t)col*KTOT + (kb + j*8));
    }
  };

  const f32x4 zero4 = {0.f,0.f,0.f,0.f};
  f32x4 acc[NCf];
  #pragma unroll
  for(int c=0;c<NCf;c++) acc[c] = zero4;

  load_regs(0);
  for(int it=0; it<ITERS; ++it){
    const int buf = it & 1;
    #pragma unroll
    for(int c=0;c<2;c++){
      const int d = c*256 + tid, r = d>>3, j = d&7;
      *(bf16x8*)(&Abuf[buf][r*BK + ((j ^ (r&7))*8)]) = ra[c];
    }
    #pragma unroll
    for(int c=0;c<BCN;c++){
      const int d = c*256 + tid, col = d>>3, j = d&7;
      *(bf16x8*)(&Bbuf[buf][col*BK + ((j ^ (col&7))*8)]) = rb[c];
    }
    __syncthreads();
    if(it+1 < ITERS) load_regs(it+1);
    const int arow = wv*16 + (l&15);
    #pragma unroll
    for(int ks=0; ks<2; ++ks){
      const int chq = ks*4 + (l>>4);
      bf16x8 a = *(const bf16x8*)(&Abuf[buf][arow*BK + ((chq ^ (arow&7))*8)]);
      #pragma unroll
      for(int c=0;c<NCf;c++){
        const int cc = c*16 + (l&15);
        bf16x8 b = *(const bf16x8*)(&Bbuf[buf][cc*BK + ((chq ^ (cc&7))*8)]);
        acc[c] = mfma16(a, b, acc[c]);
      }
    }
    __syncthreads();
  }
  const int rbase = mblk*BM + wv*16 + (l>>4)*4;
  #pragma unroll
  for(int c=0;c<NCf;c++){
    const int col = c*16 + (l&15);
    #pragma unroll
    for(int j=0;j<4;j++)
      Cpart[((size_t)split*8192 + rbase + j)*NC + col] = acc[c][j];
  }
}

// ---------------- decoder fused GRU cell (one barrier, wave-local loop body) ----------------
template<int XC, bool DEC>
__global__ __launch_bounds__(256)
void k_gru(float* __restrict__ h,
           const float* __restrict__ Cpart,
           const unsigned short* __restrict__ Wzr_hi, const unsigned short* __restrict__ Wzr_lo,
           const unsigned short* __restrict__ Wh_hi,  const unsigned short* __restrict__ Wh_lo,
           const float* __restrict__ bzr, const float* __restrict__ bhf,
           const float* __restrict__ g, const float* __restrict__ beta,
           const float* __restrict__ fcW, const float* __restrict__ fcb,
           float* __restrict__ out, unsigned short* __restrict__ XrD, int t)
{
  constexpr int NCIN = (XC==4)?64:32;
  constexpr int PAD0 = XC + 64;
  __shared__ __align__(16) unsigned short A_[64*128];   // 16 KB
  __shared__ __align__(16) unsigned short Wzr[12288];   // 24 KB (zr hi)
  __shared__ __align__(16) unsigned short Whh[6144];    // 12 KB (h hi)
  (void)Wzr_lo;
  const int tid = threadIdx.x, wv = tid>>6, l = tid&63;
  const int rb = blockIdx.x * 64;
  const int wr = wv*16, lrow0 = (l>>4)*4;
  const f32x4 zero4 = {0.f,0.f,0.f,0.f};

  for(int i=tid; i<1536; i+=256) ((bf16x8*)Wzr)[i] = ((const bf16x8*)Wzr_hi)[i];
  for(int i=tid; i<768;  i+=256) ((bf16x8*)Whh)[i] = ((const bf16x8*)Wh_hi)[i];
  for(int z=tid; z<64*(96-PAD0); z+=256){
    const int r = z/(96-PAD0), col = PAD0 + z%(96-PAD0);
    A_[swz(r,col)] = 0;
  }
  if(tid < 64*XC){
    const int r = tid/XC, col = tid%XC;
    const int grow = rb + r;
    const int b = grow >> 12, n = grow & 4095;
    const int sup = (XC==4)? (col>>1) : col;
    const int ccol = (XC==4)? ((b<<1) | (col&1)) : b;
    const size_t cr = (size_t)sup*4096 + n;
    const float v = Cpart[(0*(size_t)8192 + cr)*NCIN + ccol]
                  + Cpart[(1*(size_t)8192 + cr)*NCIN + ccol]
                  + Cpart[(2*(size_t)8192 + cr)*NCIN + ccol]
                  + Cpart[(3*(size_t)8192 + cr)*NCIN + ccol];
    A_[swz(r,col)] = cvt1(v);
  }
  float hv[4][4];
  #pragma unroll
  for(int c=0;c<4;c++){
    #pragma unroll
    for(int j=0;j<4;j++){
      const float hval = h[(size_t)(rb + wr + lrow0 + j)*64 + c*16 + (l&15)];
      hv[c][j] = hval;
      A_[swz(wr+lrow0+j, XC + c*16 + (l&15))] = cvt1(hval);
    }
  }
  __syncthreads();   // single barrier: covers cross-wave x/pad/W staging

  bf16x8 af[3];
  {
    const int arow = wr + (l&15);
    #pragma unroll
    for(int ks=0;ks<3;ks++)
      af[ks] = *(const bf16x8*)(&A_[arow*128 + (((ks*4 + (l>>4)) ^ (arow&7))*8)]);
  }
  float zv[4][4], rv[4][4];
  #pragma unroll
  for(int c=0;c<8;c++){
    f32x4 acc = zero4;
    #pragma unroll
    for(int ks=0;ks<3;ks++){
      const bf16x8 whi = *(const bf16x8*)(&Wzr[(((ks*8 + c)*64 + l)*8)]);
      acc = mfma16(af[ks], whi, acc);
    }
    const float bias = bzr[c*16 + (l&15)];
    #pragma unroll
    for(int j=0;j<4;j++){
      const float s = sig2_(acc[j] + bias);
      if(c<4) zv[c][j] = s; else rv[c-4][j] = s;
    }
  }
  // restage r*h (wave-local rows; in-order LDS pipe orders WAR/RAW)
  #pragma unroll
  for(int c=0;c<4;c++){
    #pragma unroll
    for(int j=0;j<4;j++)
      A_[swz(wr+lrow0+j, XC + c*16 + (l&15))] = cvt1(rv[c][j]*hv[c][j]);
  }

  float ht[4][4];
  {
    const int arow = wr + (l&15);
    bf16x8 a2[3];
    #pragma unroll
    for(int ks=0;ks<3;ks++)
      a2[ks] = *(const bf16x8*)(&A_[arow*128 + (((ks*4 + (l>>4)) ^ (arow&7))*8)]);
    #pragma unroll
    for(int c=0;c<4;c++){
      f32x4 acc = zero4;
      #pragma unroll
      for(int ks=0;ks<3;ks++){
        const bf16x8 whi = *(const bf16x8*)(&Whh[(((ks*4 + c)*64 + l)*8)]);
        const bf16x8 wlo = *(const bf16x8*)(Wh_lo + (((ks*4 + c)*64 + l)*8));
        acc = mfma16(a2[ks], whi, acc);
        acc = mfma16(a2[ks], wlo, acc);
      }
      const float bias = bhf[c*16 + (l&15)];
      #pragma unroll
      for(int j=0;j<4;j++) ht[c][j] = tanh2_(acc[j] + bias);
    }
  }

  float onew[4][4];
  #pragma unroll
  for(int j=0;j<4;j++){
    float hn[4];
    float s=0.f, q2=0.f;
    #pragma unroll
    for(int c=0;c<4;c++){
      const float v = (1.f - zv[c][j])*hv[c][j] + zv[c][j]*ht[c][j];
      hn[c]=v; s += v; q2 += v*v;
    }
    s = dpp_red16(s); q2 = dpp_red16(q2);
    const float mu = s*(1.f/64.f);
    const float var = q2*(1.f/64.f) - mu*mu;
    const float rs = rsqrtf(var + 1e-5f);
    #pragma unroll
    for(int c=0;c<4;c++){
      const int col = c*16 + (l&15);
      onew[c][j] = (hn[c]-mu)*rs*g[col] + beta[col];
    }
  }
  #pragma unroll
  for(int c=0;c<4;c++){
    const int col = c*16 + (l&15);
    #pragma unroll
    for(int j=0;j<4;j++)
      h[(size_t)(rb + wr + lrow0 + j)*64 + col] = onew[c][j];
  }
  if constexpr (DEC){
    #pragma unroll
    for(int j=0;j<4;j++){
      float fs = 0.f;
      #pragma unroll
      for(int c=0;c<4;c++) fs += onew[c][j]*fcW[c*16 + (l&15)];
      fs = dpp_red16(fs);
      if((l&15)==0){
        const int grow = rb + wr + lrow0 + j;
        const int b = grow>>12, n = grow & 4095;
        const float y = fs + fcb[0];
        out[((size_t)b*12 + t)*4096 + n] = y;
        XrD[(size_t)b*4096 + n] = f2bf(y);
      }
    }
  }
}

// ---------------- launch ----------------

extern "C" void kernel_launch(void* const* d_in, const int* in_sizes, int n_in,
                              void* d_out, int out_size, void* d_ws, size_t ws_size,
                              hipStream_t stream)
{
  (void)in_sizes; (void)n_in;
  const float* X   = (const float*)d_in[0];
  const float* sup = (const float*)d_in[1];
  const float* eWz = (const float*)d_in[2];
  const float* ebz = (const float*)d_in[3];
  const float* eWr = (const float*)d_in[4];
  const float* ebr = (const float*)d_in[5];
  const float* eWh = (const float*)d_in[6];
  const float* ebh = (const float*)d_in[7];
  const float* eg  = (const float*)d_in[8];
  const float* ebt = (const float*)d_in[9];
  const float* dWz = (const float*)d_in[10];
  const float* dbz = (const float*)d_in[11];
  const float* dWr = (const float*)d_in[12];
  const float* dbr = (const float*)d_in[13];
  const float* dWh = (const float*)d_in[14];
  const float* dbh = (const float*)d_in[15];
  const float* dg  = (const float*)d_in[16];
  const float* dbt = (const float*)d_in[17];
  const float* fcW = (const float*)d_in[18];
  const float* fcb = (const float*)d_in[19];
  float* out = (float*)d_out;

  char* ws = (char*)d_ws;
  const size_t OFF_AS  = 0;                    // 67,108,864  As bf16 [8192][4096]
  const size_t OFF_H   = 67108864;             // 33,554,432  h f32 (logical layout)
  const size_t OFF_CPE = 100663296;            // 25,165,824  Cp_enc f32 [12][8192][64]
  const size_t OFF_CPD = 125829120;            //  4,194,304  Cp_dec f32 [4][8192][32]
  const size_t OFF_XRE = 130023424;            //  6,291,456  XrE bf16
  const size_t OFF_XRD = 136314880;            //    262,144  XrD bf16
  const size_t OFF_P   = 136577024;            //    147,456 B shorts + 1,536 B bias floats
  const size_t NEED    = OFF_P + 147456 + 1536;
  if(ws_size < NEED){
    k_sentinel<<<(out_size+255)/256,256,0,stream>>>(out, out_size);
    return;
  }
  unsigned short* As  = (unsigned short*)(ws + OFF_AS);
  float* h            = (float*)(ws + OFF_H);
  float* CpE          = (float*)(ws + OFF_CPE);
  float* CpD          = (float*)(ws + OFF_CPD);
  unsigned short* XrE = (unsigned short*)(ws + OFF_XRE);
  unsigned short* XrD = (unsigned short*)(ws + OFF_XRD);
  unsigned short* P   = (unsigned short*)(ws + OFF_P);
  const float* Pf     = (const float*)(ws + OFF_P + 147456);

  k_conv_bf16<<<16384,256,0,stream>>>(sup, As, 4194304);
  k_pack_w<<<146,256,0,stream>>>(eWz,eWr,eWh,dWz,dWr,dWh,
                                 ebz,ebr,ebh,dbz,dbr,dbh,P);
  k_build_xre<<<1536,256,0,stream>>>(X, XrE);

  // encoder: one batched diffusion GEMM + one fused 12-step GRU kernel
  k_enc_gemm<<<512,256,0,stream>>>(As, XrE, CpE);
  k_enc_fused<<<2048,256,0,stream>>>(h, CpE, P, Pf+0, Pf+128, eg, ebt);

  // decoder: sequential (y feeds back through global diffusion)
  hipMemsetAsync(CpD, 0, 4194304, stream);   // t=0: y=0 -> x_cat=0
  for(int t=0;t<12;t++){
    if(t>0) k_diff_gemm<32><<<dim3(128,4),256,0,stream>>>(As, XrD, CpD);
    k_gru<2,true><<<2048,256,0,stream>>>(h, CpD, P+36864, P+49152, P+61440, P+67584,
        Pf+192, Pf+320, dg, dbt, fcW, fcb, out, XrD, t);
  }
}